// Round 7
// baseline (118.520 us; speedup 1.0000x reference)
//
#include <hip/hip_runtime.h>

// ACELoss3D round 17: R16 champion skeleton + packed-FP32 (v_pk_*) math.
// R16 confirmed ace_main is VALU issue-rate bound: ~190 VALU inst/thread x
// 2cyc x 192 waves/CU ~= 30us = measured. gfx950 has full-rate packed fp32
// (VOP3P v_pk_fma/add/mul_f32); the 4 z-elems/thread are data-parallel, so
// the math section is rewritten as two float2 pairs (a,b)/(c,d) via
// ext_vector_type + __builtin_elementwise_fma -> LLVM selects v_pk ops.
// float4 loads already place pair components in adjacent VGPRs. Per-lane pk
// ops are bit-identical IEEE ops in the same association order.
// Shuffles / loads / reductions / skeleton: unchanged from R16.
// History: R10 119.7; R11 coop launch no-op under graph capture; R12 agent
// fences 518; R13 single-address atomics +55us tail; R14 125.5; R15 128.2;
// R16 exact VALU cuts (sgn^2=1, region identity t(t-2u)+u) -> 117.2 champ.

static constexpr int   NTOT   = 6 * 128 * 128 * 128;   // 12,582,912
static constexpr int   NBLK   = 6144;                  // 32x32 xy-tiles * 6 bc
static constexpr float ALPHA_ = 0.001f;
static constexpr float EPS_   = 1e-8f;

typedef float v2 __attribute__((ext_vector_type(2)));

__device__ __forceinline__ v2 fma2(v2 a, v2 b, v2 c) {
#if defined(__has_builtin) && __has_builtin(__builtin_elementwise_fma)
  return __builtin_elementwise_fma(a, b, c);
#else
  return (v2){fmaf(a.x, b.x, c.x), fmaf(a.y, b.y, c.y)};
#endif
}

__device__ __forceinline__ void wave_reduce1(float& a) {
#pragma unroll
  for (int off = 32; off > 0; off >>= 1) a += __shfl_down(a, off);
}

// Two output elements at once (packed). di/dj un-halved first diffs; sx/sy =
// uxp+uxm, uyp+uym; dik/djk/dij un-halved mixed double-diffs.
// 2*cik*cjk*cij = 0.25*dik*djk*dij. Region: t*(t-2u)+u (exact, R16-verified).
__device__ __forceinline__ void elem2(
    v2 uzm, v2 u0, v2 uzp,
    v2 di, v2 sx, v2 dj, v2 sy,
    v2 dik, v2 djk, v2 dij,
    v2 t, v2& s12, v2& s3) {
  const v2 dk  = uzp - uzm;
  const v2 ci2 = (0.25f * di) * di;
  const v2 cj2 = (0.25f * dj) * dj;
  const v2 ck2 = (0.25f * dk) * dk;
  const v2 u2  = u0 + u0;
  const v2 cii = sx - u2;
  const v2 cjj = sy - u2;
  const v2 ckk = (uzp + uzm) - u2;
  const v2 ss  = ci2 + cj2 + ck2;
  const v2 ss1 = 1.f + ss;
  const v2 L = (cii + cjj) + ckk;
  const v2 M = fma2(ci2, cii, fma2(cj2, cjj, ck2 * ckk));
  v2 curv = fma2(ss1, L, -M);
  curv = fma2(-0.25f * dij, dik * djk, curv);
  const v2 e = EPS_ + ss;
  // TRANS pipe has no packed form: scalar sqrt/rcp per component.
  const v2 lr = { __builtin_amdgcn_sqrtf(e.x) * __builtin_amdgcn_rcpf(ss1.x),
                  __builtin_amdgcn_sqrtf(e.y) * __builtin_amdgcn_rcpf(ss1.y) };
  s3 = fma2(curv * curv, lr, s3);
  const v2 m2 = {-2.f, -2.f};
  s12 = s12 + fma2(t, fma2(m2, u0, t), u0);   // u(t-1)^2+(1-u)t^2
}

__global__ __launch_bounds__(512, 4) void ace_main(
    const float* __restrict__ pred, const float* __restrict__ truth,
    float* __restrict__ partials) {
  const int tid = threadIdx.x;
  // Block -> (bc, y-tile, x-tile); thread -> (x-sub, y-sub, z-group).
  const int rem = blockIdx.x & 1023;        // 32x32 xy tiles
  const int bc  = blockIdx.x >> 10;         // 0..5
  const int x   = ((rem & 31) << 2)  + (tid >> 7);
  const int y   = ((rem >> 5) << 2)  + ((tid >> 5) & 3);
  const int z0  = (tid & 31) << 2;                         // 0,4,...,124
  const size_t base = ((size_t)bc) << 21;
  const float* __restrict__ bp = pred + base;

  // Wave halves: lanes 0-31 = even y-sub, lanes 32-63 = odd y-sub (adjacent y).
  const bool upper = (tid & 32) != 0;
  const int yOut = upper ? ((y < 127) ? y + 1 : 127) : ((y > 0) ? y - 1 : 0);
  const int rO  = yOut << 7;
  const int rC  = y << 7;
  const int pC  = x << 14;
  const int pXp = ((x < 127) ? x + 1 : 127) << 14;
  const int pXm = ((x > 0)   ? x - 1 : 0)   << 14;

  // 7 float4 loads — all pinned in flight before any consumer.
  const float4 vC  = *(const float4*)(bp + pC  + rC + z0);
  const float4 vXP = *(const float4*)(bp + pXp + rC + z0);
  const float4 vXM = *(const float4*)(bp + pXm + rC + z0);
  const float4 vOY = *(const float4*)(bp + pC  + rO + z0);   // outward y row
  const float4 vOP = *(const float4*)(bp + pXp + rO + z0);
  const float4 vOM = *(const float4*)(bp + pXm + rO + z0);
  const float4 t4  = *(const float4*)(truth + base + pC + rC + z0);
#if defined(__has_builtin)
#if __has_builtin(__builtin_amdgcn_sched_barrier)
  __builtin_amdgcn_sched_barrier(0);   // keep all 7 loads issued before math
#endif
#endif

  // Pair views of the loaded rows (adjacent VGPRs -> free).
  const v2* vCp  = (const v2*)&vC;
  const v2* vXPp = (const v2*)&vXP;
  const v2* vXMp = (const v2*)&vXM;
  const v2* vOYp = (const v2*)&vOY;
  const v2* vOPp = (const v2*)&vOP;
  const v2* vOMp = (const v2*)&vOM;
  const v2* t4p  = (const v2*)&t4;

  // Center-row x combines (packed: 4 scalar ops -> 2 pk ops each).
  const v2 dx01 = vXPp[0] - vXMp[0], dx23 = vXPp[1] - vXMp[1];
  const v2 sx01 = vXPp[0] + vXMp[0], sx23 = vXPp[1] + vXMp[1];
  const v2 dO01 = vOPp[0] - vOMp[0], dO23 = vOPp[1] - vOMp[1];
  const float dxa = dx01.x, dxb = dx01.y, dxc = dx23.x, dxd = dx23.y;

  // Inward y-neighbor via half-wave exchange (partner row is never clamped).
  const float iCa = __shfl_xor(vC.x, 32), iCb = __shfl_xor(vC.y, 32);
  const float iCc = __shfl_xor(vC.z, 32), iCd = __shfl_xor(vC.w, 32);
  const float iDa = __shfl_xor(dxa, 32),  iDb = __shfl_xor(dxb, 32);
  const float iDc = __shfl_xor(dxc, 32),  iDd = __shfl_xor(dxd, 32);
  const v2 iC01 = {iCa, iCb}, iC23 = {iCc, iCd};
  const v2 iD01 = {iDa, iDb}, iD23 = {iDc, iDd};

  // y combines — sign-free (R16: sgn^2=1 in dij*djk; dj only as dj^2/sy).
  const v2 sy01 = iC01 + vOYp[0], sy23 = iC23 + vOYp[1];
  const v2 dy01 = vOYp[0] - iC01, dy23 = vOYp[1] - iC23;
  const v2 j01  = dO01 - iD01,    j23  = dO23 - iD23;
  const float dya = dy01.x, dyb = dy01.y, dyc = dy23.x, dyd = dy23.y;

  // z-halo from adjacent lanes (lane i-1 holds z0-4..z0-1). Clamp lanes
  // (tid&31)==0 / ==31 are select-overridden, so the +-1 shuffles never leak
  // across the 32-lane z-line boundary (where y changes).
  const bool zlo = (z0 == 0), zhi = (z0 == 124);
  float clo  = __shfl_up  (vC.w, 1);  clo  = zlo ? vC.x : clo;
  float chi  = __shfl_down(vC.x, 1);  chi  = zhi ? vC.w : chi;
  float dxm1 = __shfl_up  (dxd, 1);   dxm1 = zlo ? dxa : dxm1;
  float dxp4 = __shfl_down(dxa, 1);   dxp4 = zhi ? dxd : dxp4;
  float dym1 = __shfl_up  (dyd, 1);   dym1 = zlo ? dya : dym1;
  float dyp4 = __shfl_down(dya, 1);   dyp4 = zhi ? dyd : dyp4;

  v2 s12 = {0.f, 0.f}, s3 = {0.f, 0.f};
  // Pair (a,b): uzm={clo,vC.x}, u0=vC.xy, uzp=vC.yz.
  elem2((v2){clo, vC.x}, vCp[0], (v2){vC.y, vC.z},
        dx01, sx01, dy01, sy01,
        (v2){dxb - dxm1, dxc - dxa}, (v2){dyb - dym1, dyc - dya}, j01,
        t4p[0], s12, s3);
  // Pair (c,d): uzm=vC.yz, u0=vC.zw, uzp={vC.w,chi}.
  elem2((v2){vC.y, vC.z}, vCp[1], (v2){vC.w, chi},
        dx23, sx23, dy23, sy23,
        (v2){dxd - dxb, dxp4 - dxc}, (v2){dyd - dyb, dyp4 - dyc}, j23,
        t4p[1], s12, s3);

  // Single scalar per thread (MIU=1, abs no-ops) -> 1-value reduce, 1 partial.
  const v2 st = s12 + s3;
  float v = st.x + st.y;
  wave_reduce1(v);
  __shared__ float l[8];
  const int lane = tid & 63, wv = tid >> 6;
  if (lane == 0) l[wv] = v;
  __syncthreads();
  if (tid == 0) {
    float p = 0.f;
#pragma unroll
    for (int w = 0; w < 8; ++w) p += l[w];
    partials[blockIdx.x] = p;
  }
}

__global__ __launch_bounds__(1024) void ace_final(
    const float* __restrict__ partials, float* __restrict__ out) {
  const int tid = threadIdx.x;
  float s = 0.f;
  const float4* p4 = (const float4*)partials;   // 6144 floats = 1536 float4
#pragma unroll
  for (int i = tid; i < NBLK / 4; i += 1024) {
    const float4 a = p4[i];
    s += (a.x + a.y) + (a.z + a.w);
  }
  wave_reduce1(s);
  __shared__ float l[16];
  const int lane = tid & 63, wv = tid >> 6;
  if (lane == 0) l[wv] = s;
  __syncthreads();
  if (tid == 0) {
    float S = 0.f;
#pragma unroll
    for (int w = 0; w < 16; ++w) S += l[w];
    out[0] = S + ALPHA_ * (float)NTOT;
  }
}

extern "C" void kernel_launch(void* const* d_in, const int* in_sizes, int n_in,
                              void* d_out, int out_size, void* d_ws, size_t ws_size,
                              hipStream_t stream) {
  const float* pred  = (const float*)d_in[0];   // y_pred
  const float* truth = (const float*)d_in[1];   // y_true
  float* out      = (float*)d_out;
  float* partials = (float*)d_ws;               // NBLK floats = 24.6 KB

  ace_main<<<NBLK, 512, 0, stream>>>(pred, truth, partials);
  ace_final<<<1, 1024, 0, stream>>>(partials, out);
}

// Round 9
// 116.745 us; speedup vs baseline: 1.0152x; 1.0152x over previous
//
#include <hip/hip_runtime.h>

// ACELoss3D round 19: R18 retry — DPP ctrl as template arg (ICE requirement).
// R18 failed to compile: __builtin_amdgcn_update_dpp needs a constant-integer
// dpp_ctrl; runtime arg rejected before inlining. Theory unchanged:
// __shfl_* compiles to ds_bpermute -> 20 DS ops/thread (~10us DS-busy/CU)
// with serial chain segments (6-step reduce ~700cyc all-waves; z-halo mid-
// chain). Convert z-halo shifts + wave reduction to VALU DPP:
//  - shfl_up/down(1)  -> v_mov_dpp wave_shr:1 / wave_shl:1 (invalid + cross-
//    row lanes are exactly the zlo/zhi select-overridden lanes);
//  - wave reduce      -> gfx9 DPP ladder (row_shr:1/2/4/8, row_bcast:15/31,
//    readlane 63). Different association order => absmax ulp-level, not 0.
// y-exchange keeps __shfl_xor(,32): 8 independent DS ops, latency amortized.
// History: R10 119.7; R11 coop no-op; R12 fences 518; R13 atomic tail; R14
// 125.5; R15 128.2; R16 exact-algebra cuts 117.2 CHAMP; R17 pk-fp32 118.5
// (fp32 peak = scalar rate on gfx950); R18 compile error (non-ICE dpp ctrl).

static constexpr int   NTOT   = 6 * 128 * 128 * 128;   // 12,582,912
static constexpr int   NBLK   = 6144;                  // 32x32 xy-tiles * 6 bc
static constexpr float ALPHA_ = 0.001f;
static constexpr float EPS_   = 1e-8f;

// ---- DPP helpers (all VALU; no DS pipe, no lgkmcnt) ----
template <int CTRL>
__device__ __forceinline__ float dpp_mov(float x) {
  return __int_as_float(__builtin_amdgcn_update_dpp(
      0, __float_as_int(x), CTRL, 0xf, 0xf, true));   // invalid lanes -> 0
}
__device__ __forceinline__ float dpp_up1(float x) {   // == __shfl_up(x,1)
  return dpp_mov<0x138>(x);                           // wave_shr:1
}
__device__ __forceinline__ float dpp_dn1(float x) {   // == __shfl_down(x,1)
  return dpp_mov<0x130>(x);                           // wave_shl:1
}
// Full wave64 sum in 6 VALU adds; total lands in lane 63.
__device__ __forceinline__ float wave_sum(float v) {
  v += dpp_mov<0x111>(v);   // row_shr:1
  v += dpp_mov<0x112>(v);   // row_shr:2
  v += dpp_mov<0x114>(v);   // row_shr:4
  v += dpp_mov<0x118>(v);   // row_shr:8  -> lane 15/31/47/63 = row sums
  v += dpp_mov<0x142>(v);   // row_bcast:15 -> lane 31/63 = half sums
  v += dpp_mov<0x143>(v);   // row_bcast:31 -> lane 63 = wave sum
  return __int_as_float(
      __builtin_amdgcn_readlane(__float_as_int(v), 63));
}

// One output element. di/dj = un-halved first diffs (sign-free, R16); sx/sy =
// uxp+uxm, uyp+uym; dik/djk/dij = un-halved mixed double-diffs.
// 2*cik*cjk*cij = 0.25*dik*djk*dij. Region: t*(t-2u)+u (exact, R16-verified).
__device__ __forceinline__ void elem(
    float uzm, float u0, float uzp,
    float di, float sx, float dj, float sy,
    float dik, float djk, float dij,
    float t, float& s12, float& s3) {
  const float dk  = uzp - uzm;
  const float ci2 = 0.25f * di * di;
  const float cj2 = 0.25f * dj * dj;
  const float ck2 = 0.25f * dk * dk;
  const float u2  = u0 + u0;
  const float cii = sx - u2;
  const float cjj = sy - u2;
  const float ckk = (uzp + uzm) - u2;
  const float ss  = ci2 + cj2 + ck2;
  const float ss1 = 1.f + ss;
  const float L = (cii + cjj) + ckk;
  const float M = fmaf(ci2, cii, fmaf(cj2, cjj, ck2 * ckk));
  float curv = fmaf(ss1, L, -M);
  curv = fmaf(-0.25f * dij, dik * djk, curv);
  const float len = __builtin_amdgcn_sqrtf(EPS_ + ss);
  s3 = fmaf(curv * curv, len * __builtin_amdgcn_rcpf(ss1), s3);
  s12 += fmaf(t, fmaf(-2.f, u0, t), u0);    // u(t-1)^2+(1-u)t^2
}

__global__ __launch_bounds__(512, 4) void ace_main(
    const float* __restrict__ pred, const float* __restrict__ truth,
    float* __restrict__ partials) {
  const int tid = threadIdx.x;
  // Block -> (bc, y-tile, x-tile); thread -> (x-sub, y-sub, z-group).
  const int rem = blockIdx.x & 1023;        // 32x32 xy tiles
  const int bc  = blockIdx.x >> 10;         // 0..5
  const int x   = ((rem & 31) << 2)  + (tid >> 7);
  const int y   = ((rem >> 5) << 2)  + ((tid >> 5) & 3);
  const int z0  = (tid & 31) << 2;                         // 0,4,...,124
  const size_t base = ((size_t)bc) << 21;
  const float* __restrict__ bp = pred + base;

  // Wave halves: lanes 0-31 = even y-sub, lanes 32-63 = odd y-sub (adjacent y).
  const bool upper = (tid & 32) != 0;
  const int yOut = upper ? ((y < 127) ? y + 1 : 127) : ((y > 0) ? y - 1 : 0);
  const int rO  = yOut << 7;
  const int rC  = y << 7;
  const int pC  = x << 14;
  const int pXp = ((x < 127) ? x + 1 : 127) << 14;
  const int pXm = ((x > 0)   ? x - 1 : 0)   << 14;

  // 7 float4 loads — all pinned in flight before any consumer.
  const float4 vC  = *(const float4*)(bp + pC  + rC + z0);
  const float4 vXP = *(const float4*)(bp + pXp + rC + z0);
  const float4 vXM = *(const float4*)(bp + pXm + rC + z0);
  const float4 vOY = *(const float4*)(bp + pC  + rO + z0);   // outward y row
  const float4 vOP = *(const float4*)(bp + pXp + rO + z0);
  const float4 vOM = *(const float4*)(bp + pXm + rO + z0);
  const float4 t4  = *(const float4*)(truth + base + pC + rC + z0);
#if defined(__has_builtin)
#if __has_builtin(__builtin_amdgcn_sched_barrier)
  __builtin_amdgcn_sched_barrier(0);   // keep all 7 loads issued before math
#endif
#endif

  // Center-row x combines.
  const float dxa = vXP.x - vXM.x, dxb = vXP.y - vXM.y;
  const float dxc = vXP.z - vXM.z, dxd = vXP.w - vXM.w;
  const float sxa = vXP.x + vXM.x, sxb = vXP.y + vXM.y;
  const float sxc = vXP.z + vXM.z, sxd = vXP.w + vXM.w;
  // Outward-row x-diff.
  const float dOa = vOP.x - vOM.x, dOb = vOP.y - vOM.y;
  const float dOc = vOP.z - vOM.z, dOd = vOP.w - vOM.w;

  // Inward y-neighbor via half-wave exchange (partner row is never clamped).
  const float iCa = __shfl_xor(vC.x, 32), iCb = __shfl_xor(vC.y, 32);
  const float iCc = __shfl_xor(vC.z, 32), iCd = __shfl_xor(vC.w, 32);
  const float iDa = __shfl_xor(dxa, 32),  iDb = __shfl_xor(dxb, 32);
  const float iDc = __shfl_xor(dxc, 32),  iDd = __shfl_xor(dxd, 32);

  // y combines — sign-free (R16: sgn^2=1 in dij*djk; dj only as dj^2/sy).
  const float sya = iCa + vOY.x, syb = iCb + vOY.y;
  const float syc = iCc + vOY.z, syd = iCd + vOY.w;
  const float dya = vOY.x - iCa, dyb = vOY.y - iCb;
  const float dyc = vOY.z - iCc, dyd = vOY.w - iCd;
  const float ja  = dOa - iDa,   jb  = dOb - iDb;
  const float jc  = dOc - iDc,   jd  = dOd - iDd;

  // z-halo via DPP wave shifts (VALU, was ds_bpermute). Invalid lanes (0 for
  // shr, 63 for shl) and the cross-row lanes (31<->32) are exactly the lanes
  // the zlo/zhi selects override — the shifts never leak a wrong value.
  const bool zlo = (z0 == 0), zhi = (z0 == 124);
  float clo  = dpp_up1(vC.w);  clo  = zlo ? vC.x : clo;
  float chi  = dpp_dn1(vC.x);  chi  = zhi ? vC.w : chi;
  float dxm1 = dpp_up1(dxd);   dxm1 = zlo ? dxa : dxm1;
  float dxp4 = dpp_dn1(dxa);   dxp4 = zhi ? dxd : dxp4;
  float dym1 = dpp_up1(dyd);   dym1 = zlo ? dya : dym1;
  float dyp4 = dpp_dn1(dya);   dyp4 = zhi ? dyd : dyp4;

  float s12 = 0.f, s3 = 0.f;
  elem(clo,  vC.x, vC.y, dxa, sxa, dya, sya, dxb - dxm1, dyb - dym1, ja, t4.x, s12, s3);
  elem(vC.x, vC.y, vC.z, dxb, sxb, dyb, syb, dxc - dxa,  dyc - dya,  jb, t4.y, s12, s3);
  elem(vC.y, vC.z, vC.w, dxc, sxc, dyc, syc, dxd - dxb,  dyd - dyb,  jc, t4.z, s12, s3);
  elem(vC.z, vC.w, chi,  dxd, sxd, dyd, syd, dxp4 - dxc, dyp4 - dyc, jd, t4.w, s12, s3);

  // Single scalar per thread; DPP wave sum (6 VALU adds, no DS chain).
  const float wsum = wave_sum(s12 + s3);
  __shared__ float l[8];
  const int lane = tid & 63, wv = tid >> 6;
  if (lane == 0) l[wv] = wsum;
  __syncthreads();
  if (tid == 0) {
    float p = 0.f;
#pragma unroll
    for (int w = 0; w < 8; ++w) p += l[w];
    partials[blockIdx.x] = p;
  }
}

__global__ __launch_bounds__(1024) void ace_final(
    const float* __restrict__ partials, float* __restrict__ out) {
  const int tid = threadIdx.x;
  float s = 0.f;
  const float4* p4 = (const float4*)partials;   // 6144 floats = 1536 float4
#pragma unroll
  for (int i = tid; i < NBLK / 4; i += 1024) {
    const float4 a = p4[i];
    s += (a.x + a.y) + (a.z + a.w);
  }
  const float wsum = wave_sum(s);
  __shared__ float l[16];
  const int lane = tid & 63, wv = tid >> 6;
  if (lane == 0) l[wv] = wsum;
  __syncthreads();
  if (tid == 0) {
    float S = 0.f;
#pragma unroll
    for (int w = 0; w < 16; ++w) S += l[w];
    out[0] = S + ALPHA_ * (float)NTOT;
  }
}

extern "C" void kernel_launch(void* const* d_in, const int* in_sizes, int n_in,
                              void* d_out, int out_size, void* d_ws, size_t ws_size,
                              hipStream_t stream) {
  const float* pred  = (const float*)d_in[0];   // y_pred
  const float* truth = (const float*)d_in[1];   // y_true
  float* out      = (float*)d_out;
  float* partials = (float*)d_ws;               // NBLK floats = 24.6 KB

  ace_main<<<NBLK, 512, 0, stream>>>(pred, truth, partials);
  ace_final<<<1, 1024, 0, stream>>>(partials, out);
}